// Round 1
// baseline (205.340 us; speedup 1.0000x reference)
//
#include <hip/hip_runtime.h>
#include <math.h>

#define SZ 256
#define KNN 4
#define NUM_CHANNELS 8

// Exact top-4 maintenance: keys sorted ascending, key = (d2_int << 16) | flat_idx.
// Matches jax.lax.top_k semantics (smallest d2 first, ties -> lower index).
__device__ __forceinline__ void insert_key(unsigned long long key,
                                           unsigned long long& k0,
                                           unsigned long long& k1,
                                           unsigned long long& k2,
                                           unsigned long long& k3) {
    if (key < k3) {
        if (key < k2) {
            k3 = k2;
            if (key < k1) {
                k2 = k1;
                if (key < k0) { k1 = k0; k0 = key; }
                else          { k1 = key; }
            } else {
                k2 = key;
            }
        } else {
            k3 = key;
        }
    }
}

__global__ __launch_bounds__(256) void TreeMultiRandom_knn_kernel(
    const float* __restrict__ img,   // [SZ*SZ] coded[0,0]
    const int*   __restrict__ lut,   // [SZ*SZ] lookup_table
    float*       __restrict__ out)   // [NUM_CHANNELS, SZ, SZ]
{
    const int x = threadIdx.x;        // column
    const int y = blockIdx.x;         // row
    const int ch = blockIdx.y;        // 0..7
    const int c = ch + 1;             // channel value in lut
    const int pix = y * SZ + x;

    float* outc = out + (size_t)ch * (SZ * SZ);

    // Filled pixel for this channel: pass through the image value.
    if (lut[pix] == c) {
        outc[pix] = img[pix];
        return;
    }

    unsigned long long k0 = ~0ull, k1 = ~0ull, k2 = ~0ull, k3 = ~0ull;

    for (int r = 1; r <= SZ - 1; ++r) {
        const int y0 = y - r, y1 = y + r;
        const int x0 = x - r, x1 = x + r;
        const int xs = (x0 < 0) ? 0 : x0;
        const int xe = (x1 > SZ - 1) ? SZ - 1 : x1;

        // top and bottom rows of the ring (full width)
        #pragma unroll
        for (int pass = 0; pass < 2; ++pass) {
            const int yy = pass ? y1 : y0;
            if (yy < 0 || yy > SZ - 1) continue;
            const int dy = yy - y;
            const int dy2 = dy * dy;
            const int rowbase = yy * SZ;
            for (int xx = xs; xx <= xe; ++xx) {
                if (lut[rowbase + xx] == c) {
                    const int dx = xx - x;
                    const int d2 = dy2 + dx * dx;
                    const unsigned long long key =
                        ((unsigned long long)d2 << 16) | (unsigned)(rowbase + xx);
                    insert_key(key, k0, k1, k2, k3);
                }
            }
        }

        // left and right columns (corners already covered)
        const int ys = (y0 + 1 < 0) ? 0 : y0 + 1;
        const int ye = (y1 - 1 > SZ - 1) ? SZ - 1 : y1 - 1;
        #pragma unroll
        for (int pass = 0; pass < 2; ++pass) {
            const int xx = pass ? x1 : x0;
            if (xx < 0 || xx > SZ - 1) continue;
            const int dx = xx - x;
            const int dx2 = dx * dx;
            for (int yy = ys; yy <= ye; ++yy) {
                if (lut[yy * SZ + xx] == c) {
                    const int dy = yy - y;
                    const int d2 = dx2 + dy * dy;
                    const unsigned long long key =
                        ((unsigned long long)d2 << 16) | (unsigned)(yy * SZ + xx);
                    insert_key(key, k0, k1, k2, k3);
                }
            }
        }

        // A candidate at Chebyshev radius r+1 has d2 >= (r+1)^2. Strict '<' so
        // that equal-d2 candidates (lower index could win the tie) in the next
        // ring are still examined.
        const unsigned long long worst_d2 = k3 >> 16;
        if (worst_d2 < (unsigned long long)((r + 1) * (r + 1))) break;
    }

    // Weighted sum in top_k order (ascending (d2, idx)), matching the reference.
    unsigned long long ks[KNN] = { k0, k1, k2, k3 };
    float num = 0.0f, den = 0.0f;
    #pragma unroll
    for (int i = 0; i < KNN; ++i) {
        const int idx = (int)(ks[i] & 0xFFFFull);
        const int d2i = (int)(ks[i] >> 16);
        // dist = sqrt(d2_int / 65536) exactly as the reference's f32 sqrt of the
        // exactly-representable normalized d2.
        const float dist = sqrtf((float)d2i * (1.0f / 65536.0f));
        num += img[idx] * dist;
        den += dist;
    }
    outc[pix] = num / den;
}

extern "C" void kernel_launch(void* const* d_in, const int* in_sizes, int n_in,
                              void* d_out, int out_size, void* d_ws, size_t ws_size,
                              hipStream_t stream) {
    const float* img = (const float*)d_in[0];   // coded: [1,1,256,256] f32
    const int*   lut = (const int*)d_in[1];     // lookup_table: [256,256] i32
    float*       out = (float*)d_out;           // [1,8,256,256] f32

    dim3 grid(SZ, NUM_CHANNELS);
    dim3 block(SZ);
    TreeMultiRandom_knn_kernel<<<grid, block, 0, stream>>>(img, lut, out);
}